// Round 5
// baseline (198.248 us; speedup 1.0000x reference)
//
#include <hip/hip_runtime.h>

// Capsule routing, MI355X. B=2048, I=64, O=32, DI=DO=16, 3 iters.
// transpose_x: x (B,DI,I) -> xt (B,I,DI) so A-phase loads are 4x dwordx4.
// routing_kernel: block = 512 thr (8 waves), one o, 16 b's in TWO sub-rounds
//   of 8 over one 32 KB LDS priors buffer.
// Register diet for occupancy (R4: VGPR=92 -> 1.8 blocks/CU, VALUBusy 45%):
//   wave w owns d-PAIR {2w,2w+1} -> wq = 32 floats (was 64); B-phase thread
//   owns 16 i's (p[16], was 32), quarters combined via shfl_xor 16/32.
//   Peak live ~58 regs; __launch_bounds__(512,8) caps VGPR at 64 ->
//   8 waves/SIMD, 4 blocks/CU (thread cap 2048) possible.
// A-phase: lane=i; 2 FMA-chains of 16 per bb; swizzled ds_write (conflict-free,
//   bijection over the 64-word row).
// B-phase: thread=(bp=tid>>6, q=lane>>4, d=lane&15); p[16] via 4 swizzled
//   ds_read_b128; softmax combines via shfl_xor(16),(32); squash-norm over d
//   via shfl_xor 1,2,4,8. Internal barrier sits between LDS reads and compute
//   so sub-round 1's A-phase (program-order after) can't overwrite live reads.
// exp2 via __builtin_amdgcn_exp2f (|arg| <= ~115 < 127: |Vsum|<3, |p|<~26).
// Reciprocals via v_rcp (rel err ~1e-7; tolerance slack ~8x, absmax 0.002).

#define THREADS 512

__global__ __launch_bounds__(256) void transpose_x(
    const float* __restrict__ x, float* __restrict__ xt)
{
    __shared__ float t[16 * 65];            // [e][i], padded
    const int b   = blockIdx.x;
    const int tid = threadIdx.x;
    #pragma unroll
    for (int k = 0; k < 4; ++k) {
        const int idx = k * 256 + tid;      // e = idx>>6, i = idx&63
        t[(idx >> 6) * 65 + (idx & 63)] = x[b * 1024 + idx];
    }
    __syncthreads();
    const int i = tid >> 2, e4 = tid & 3;
    float4 v;
    v.x = t[(e4 * 4 + 0) * 65 + i];
    v.y = t[(e4 * 4 + 1) * 65 + i];
    v.z = t[(e4 * 4 + 2) * 65 + i];
    v.w = t[(e4 * 4 + 3) * 65 + i];
    *reinterpret_cast<float4*>(xt + b * 1024 + i * 16 + e4 * 4) = v;
}

template <bool XT>
__global__ __launch_bounds__(THREADS, 8) void routing_kernel(
    const float* __restrict__ x,    // XT ? (B,I,DI) : (B,DI,I)
    const float* __restrict__ rw,   // (O, I, DO, DI) = (32,64,16,16)
    const float* __restrict__ ns,   // same
    float* __restrict__ out)        // (1, O, B, DO)
{
    __shared__ float p_lds[8192];   // 32 KB: [row=bb*16+d][64 i, swizzled]

    const int tid  = threadIdx.x;
    const int w    = tid >> 6;      // wave 0..7
    const int lane = tid & 63;      // = i in A-phase

    const int o  = blockIdx.x >> 7;   // o-major: 128 consecutive blocks share W
    const int bc = blockIdx.x & 127;  // 16-b chunk

    // ---- W+noise fragment: lane=i, d in {2w, 2w+1} ----
    float wq[2][16];                // 32 VGPRs
    {
        const int base = (o * 64 + lane) * 256 + w * 32;
        #pragma unroll
        for (int dp = 0; dp < 2; ++dp) {
            #pragma unroll
            for (int eq = 0; eq < 4; ++eq) {
                const int idx = base + dp * 16 + eq * 4;
                const float4 a = *reinterpret_cast<const float4*>(rw + idx);
                const float4 n = *reinterpret_cast<const float4*>(ns + idx);
                wq[dp][4*eq+0] = a.x + n.x;
                wq[dp][4*eq+1] = a.y + n.y;
                wq[dp][4*eq+2] = a.z + n.z;
                wq[dp][4*eq+3] = a.w + n.w;
            }
        }
    }

    // B-phase mapping: wave = bp, lane = (q, d)
    const int qB  = lane >> 4;      // i-quarter 0..3
    const int dB  = lane & 15;
    const int swz = dB & 7;

    auto aphase = [&](int b0) {
        #pragma unroll 2
        for (int bb = 0; bb < 8; ++bb) {
            float xv[16];
            if (XT) {
                const float4* xb = reinterpret_cast<const float4*>(
                    x + (b0 + bb) * 1024 + lane * 16);
                #pragma unroll
                for (int q = 0; q < 4; ++q) {
                    const float4 v = xb[q];
                    xv[4*q+0] = v.x; xv[4*q+1] = v.y;
                    xv[4*q+2] = v.z; xv[4*q+3] = v.w;
                }
            } else {
                const float* xb = x + (b0 + bb) * 1024 + lane;
                #pragma unroll
                for (int e = 0; e < 16; ++e) xv[e] = xb[e * 64];
            }
            #pragma unroll
            for (int dp = 0; dp < 2; ++dp) {
                float acc = 0.f;
                #pragma unroll
                for (int e = 0; e < 16; ++e) acc = fmaf(wq[dp][e], xv[e], acc);
                const int d  = 2 * w + dp;
                const int fi = (bb * 16 + d) * 64
                             + ((((lane >> 2) ^ (d & 7)) << 2) | (lane & 3));
                p_lds[fi] = acc;    // one row/instr, bijective words: conflict-free
            }
        }
    };

    auto bround = [&](int b0) {
        float p[16];
        {
            const float4* pl = reinterpret_cast<const float4*>(p_lds)
                             + (w * 16 + dB) * 16;
            #pragma unroll
            for (int jj = 0; jj < 4; ++jj) {
                const float4 v = pl[(4 * qB + jj) ^ swz]; // i = qB*16+4jj..+3
                p[4*jj+0] = v.x; p[4*jj+1] = v.y;
                p[4*jj+2] = v.z; p[4*jj+3] = v.w;
            }
        }
        __syncthreads();            // reads done; next aphase may overwrite

        float part = 0.f;
        #pragma unroll
        for (int i = 0; i < 16; ++i) part += p[i];
        part += __shfl_xor(part, 16);
        part += __shfl_xor(part, 32);
        float s = part * (1.0f / 64.0f);

        float sn = s * s;           // squash norm over d (16-lane groups)
        sn += __shfl_xor(sn, 1); sn += __shfl_xor(sn, 2);
        sn += __shfl_xor(sn, 4); sn += __shfl_xor(sn, 8);
        float factor = sqrtf(sn) * __builtin_amdgcn_rcpf(1.0f + sn);
        float Vsum = s * factor;

        #pragma unroll
        for (int it = 0; it < 2; ++it) {
            const float c = Vsum * 1.44269504089f;      // log2(e)
            float den = 0.f, num = 0.f;
            #pragma unroll
            for (int i = 0; i < 16; ++i) {
                const float E = __builtin_amdgcn_exp2f(p[i] * c);
                den += E;
                num = fmaf(E, p[i], num);
            }
            den += __shfl_xor(den, 16); den += __shfl_xor(den, 32);
            num += __shfl_xor(num, 16); num += __shfl_xor(num, 32);
            s = num * __builtin_amdgcn_rcpf(den);
            sn = s * s;
            sn += __shfl_xor(sn, 1); sn += __shfl_xor(sn, 2);
            sn += __shfl_xor(sn, 4); sn += __shfl_xor(sn, 8);
            factor = sqrtf(sn) * __builtin_amdgcn_rcpf(1.0f + sn);
            Vsum += s * factor;
        }

        if (qB == 0)
            out[(o * 2048 + b0 + w) * 16 + dB] = s * factor;  // (1,O,B,DO)
    };

    const int bbase = bc * 16;

    aphase(bbase);
    __syncthreads();                // sub-round 0 priors ready
    bround(bbase);                  // reads | bar | compute + store
    aphase(bbase + 8);
    __syncthreads();                // sub-round 1 priors ready
    bround(bbase + 8);
}

extern "C" void kernel_launch(void* const* d_in, const int* in_sizes, int n_in,
                              void* d_out, int out_size, void* d_ws, size_t ws_size,
                              hipStream_t stream) {
    const float* x  = (const float*)d_in[0];
    const float* rw = (const float*)d_in[1];
    const float* ns = (const float*)d_in[2];
    float* out = (float*)d_out;
    (void)in_sizes; (void)n_in; (void)out_size;

    const int grid = 32 * 128;      // blockIdx = o*128 + bc
    const size_t xt_bytes = 2048u * 1024u * sizeof(float);

    if (ws_size >= xt_bytes) {
        float* xt = (float*)d_ws;
        transpose_x<<<2048, 256, 0, stream>>>(x, xt);
        routing_kernel<true><<<grid, THREADS, 0, stream>>>(xt, rw, ns, out);
    } else {
        routing_kernel<false><<<grid, THREADS, 0, stream>>>(x, rw, ns, out);
    }
}

// Round 6
// 136.056 us; speedup vs baseline: 1.4571x; 1.4571x over previous
//
#include <hip/hip_runtime.h>

// Capsule routing, MI355X. B=2048, I=64, O=32, DI=DO=16, 3 iters.
// Single kernel. Block = 512 thr (8 waves), one o, 16 b's in TWO sub-rounds
// of 8 over one 32 KB LDS priors buffer.
// R5 lesson (and R2): forcing min-waves (launch_bounds 2nd arg) caps VGPR
// below the live set -> scratch spills -> 2x slower. This round: same
// register-light structure as R5 but NATURAL allocation (~60-75 VGPR).
//   wave w owns d-pair {2w,2w+1}: wq = 32 floats; B-phase p[16].
//   If <=64 VGPR: 8 waves/SIMD, thread-cap 4 blocks/CU -> up to 32 waves/CU.
// No transpose pre-kernel: ws_size < 8 MB (R3/R4 WRITE_SIZE showed the XT
// path never ran); scalar x loads are coalesced (lane=i, stride-1).
// A-phase: lane=i; per bb: 16 coalesced dword loads + 2x16 FMA; swizzled
//   conflict-free ds_write (bijective over each 64-word row).
// B-phase: wave=bp, lane=(q=lane>>4, d=lane&15); p[16] via 4 swizzled
//   ds_read_b128; i-reduction: 16 serial + shfl_xor(16,32); squash-norm
//   over d: shfl_xor(1,2,4,8).
// exp2 via __builtin_amdgcn_exp2f (|arg| <= ~115 < 127: |Vsum|<3, |p|<~26).
// rcp via v_rcp (rel err ~1e-7; tolerance slack ~8x, absmax 0.002).

#define THREADS 512

__global__ __launch_bounds__(THREADS) void routing_kernel(
    const float* __restrict__ x,    // (B, DI, I) = (2048,16,64)
    const float* __restrict__ rw,   // (O, I, DO, DI) = (32,64,16,16)
    const float* __restrict__ ns,   // same
    float* __restrict__ out)        // (1, O, B, DO)
{
    __shared__ float p_lds[8192];   // 32 KB: [row=bb*16+d][64 i, swizzled]

    const int tid  = threadIdx.x;
    const int w    = tid >> 6;      // wave 0..7
    const int lane = tid & 63;      // = i in A-phase

    const int o  = blockIdx.x >> 7;   // o-major: 128 consecutive blocks share W
    const int bc = blockIdx.x & 127;  // 16-b chunk

    // ---- W+noise fragment: lane=i, d in {2w, 2w+1} ----
    float wq[2][16];                // 32 VGPRs
    {
        const int base = (o * 64 + lane) * 256 + w * 32;
        #pragma unroll
        for (int dp = 0; dp < 2; ++dp) {
            #pragma unroll
            for (int eq = 0; eq < 4; ++eq) {
                const int idx = base + dp * 16 + eq * 4;
                const float4 a = *reinterpret_cast<const float4*>(rw + idx);
                const float4 n = *reinterpret_cast<const float4*>(ns + idx);
                wq[dp][4*eq+0] = a.x + n.x;
                wq[dp][4*eq+1] = a.y + n.y;
                wq[dp][4*eq+2] = a.z + n.z;
                wq[dp][4*eq+3] = a.w + n.w;
            }
        }
    }

    // B-phase mapping: wave = bp, lane = (q, d)
    const int qB  = lane >> 4;      // i-quarter 0..3
    const int dB  = lane & 15;
    const int swz = dB & 7;

    auto aphase = [&](int b0) {
        #pragma unroll 2
        for (int bb = 0; bb < 8; ++bb) {
            const float* xb = x + (b0 + bb) * 1024 + lane;
            float xv[16];
            #pragma unroll
            for (int e = 0; e < 16; ++e) xv[e] = xb[e * 64];  // coalesced
            #pragma unroll
            for (int dp = 0; dp < 2; ++dp) {
                float acc = 0.f;
                #pragma unroll
                for (int e = 0; e < 16; ++e) acc = fmaf(wq[dp][e], xv[e], acc);
                const int d  = 2 * w + dp;
                const int fi = (bb * 16 + d) * 64
                             + ((((lane >> 2) ^ (d & 7)) << 2) | (lane & 3));
                p_lds[fi] = acc;    // bijective words per row: conflict-free
            }
        }
    };

    auto bround = [&](int b0) {
        float p[16];
        {
            const float4* pl = reinterpret_cast<const float4*>(p_lds)
                             + (w * 16 + dB) * 16;
            #pragma unroll
            for (int jj = 0; jj < 4; ++jj) {
                const float4 v = pl[(4 * qB + jj) ^ swz]; // i = qB*16+4jj..+3
                p[4*jj+0] = v.x; p[4*jj+1] = v.y;
                p[4*jj+2] = v.z; p[4*jj+3] = v.w;
            }
        }
        __syncthreads();            // reads done; next aphase may overwrite

        float part = 0.f;
        #pragma unroll
        for (int i = 0; i < 16; ++i) part += p[i];
        part += __shfl_xor(part, 16);
        part += __shfl_xor(part, 32);
        float s = part * (1.0f / 64.0f);

        float sn = s * s;           // squash norm over d (16-lane groups)
        sn += __shfl_xor(sn, 1); sn += __shfl_xor(sn, 2);
        sn += __shfl_xor(sn, 4); sn += __shfl_xor(sn, 8);
        float factor = sqrtf(sn) * __builtin_amdgcn_rcpf(1.0f + sn);
        float Vsum = s * factor;

        #pragma unroll
        for (int it = 0; it < 2; ++it) {
            const float c = Vsum * 1.44269504089f;      // log2(e)
            float den = 0.f, num = 0.f;
            #pragma unroll
            for (int i = 0; i < 16; ++i) {
                const float E = __builtin_amdgcn_exp2f(p[i] * c);
                den += E;
                num = fmaf(E, p[i], num);
            }
            den += __shfl_xor(den, 16); den += __shfl_xor(den, 32);
            num += __shfl_xor(num, 16); num += __shfl_xor(num, 32);
            s = num * __builtin_amdgcn_rcpf(den);
            sn = s * s;
            sn += __shfl_xor(sn, 1); sn += __shfl_xor(sn, 2);
            sn += __shfl_xor(sn, 4); sn += __shfl_xor(sn, 8);
            factor = sqrtf(sn) * __builtin_amdgcn_rcpf(1.0f + sn);
            Vsum += s * factor;
        }

        if (qB == 0)
            out[(o * 2048 + b0 + w) * 16 + dB] = s * factor;  // (1,O,B,DO)
    };

    const int bbase = bc * 16;

    aphase(bbase);
    __syncthreads();                // sub-round 0 priors ready
    bround(bbase);                  // reads | bar | compute + store
    aphase(bbase + 8);
    __syncthreads();                // sub-round 1 priors ready
    bround(bbase + 8);
}

extern "C" void kernel_launch(void* const* d_in, const int* in_sizes, int n_in,
                              void* d_out, int out_size, void* d_ws, size_t ws_size,
                              hipStream_t stream) {
    const float* x  = (const float*)d_in[0];
    const float* rw = (const float*)d_in[1];
    const float* ns = (const float*)d_in[2];
    float* out = (float*)d_out;
    (void)d_ws; (void)ws_size; (void)in_sizes; (void)n_in; (void)out_size;

    const int grid = 32 * 128;      // blockIdx = o*128 + bc
    routing_kernel<<<grid, THREADS, 0, stream>>>(x, rw, ns, out);
}

// Round 7
// 124.123 us; speedup vs baseline: 1.5972x; 1.0961x over previous
//
#include <hip/hip_runtime.h>

// Capsule routing, MI355X. B=2048, I=64, O=32, DI=DO=16, 3 iters.
// R6 diagnosis: L2-bound — every wave re-read x from L1/L2 (8x redundant)
// and W re-read per 16-b block => ~1.5 GB L2 traffic ~ 45 us floor.
// This round:
//   * x staged in LDS once per 8-b sub-round (coop float4 load, T14 split:
//     loads issued before bcompute, ds_write after) -> x L2 traffic /8.
//   * NB=32 per block (4 sub-rounds) -> W L2 traffic /2.
//   * Tree reductions (serial fp chains are non-reassociable by compiler).
//   * builtins exp2/rcp; natural VGPR (R2/R5 lesson: never force min-waves).
// Block = 512 thr (8 waves), one o. LDS 64 KB (p 32K + x 32K) -> 2 blocks/CU.
// A-phase: lane=i, wave w owns d-pair {2w,2w+1}; x from LDS (conflict-free
//   b32 reads); swizzled conflict-free p ds_write.
// B-phase: wave=bp, lane=(q=lane>>4, d=lane&15); p[16] via 4 swizzled
//   ds_read_b128; i-combine shfl_xor(16,32); squash-norm shfl_xor(1,2,4,8).
// exp2: |arg| <= ~115 < 127 (|Vsum|<3, |p|<~26) -> no overflow w/o max-sub.

#define THREADS 512
#define NSUB 4          // sub-rounds; NB = 8*NSUB = 32 b per block

__global__ __launch_bounds__(THREADS) void routing_kernel(
    const float* __restrict__ x,    // (B, DI, I) = (2048,16,64)
    const float* __restrict__ rw,   // (O, I, DO, DI) = (32,64,16,16)
    const float* __restrict__ ns,   // same
    float* __restrict__ out)        // (1, O, B, DO)
{
    __shared__ float lds[16384];    // [0,8192): priors; [8192,16384): x-tile
    float* p_lds = lds;
    float* x_lds = lds + 8192;

    const int tid  = threadIdx.x;
    const int w    = tid >> 6;      // wave 0..7
    const int lane = tid & 63;      // = i in A-phase

    const int o  = blockIdx.x >> 6;   // o-major: 64 consecutive blocks share W
    const int bc = blockIdx.x & 63;   // 32-b chunk
    const int bbase = bc * 32;

    // ---- W+noise fragment: lane=i, d in {2w, 2w+1} (32 VGPR) ----
    float wq[2][16];
    {
        const int base = (o * 64 + lane) * 256 + w * 32;
        #pragma unroll
        for (int dp = 0; dp < 2; ++dp) {
            #pragma unroll
            for (int eq = 0; eq < 4; ++eq) {
                const int idx = base + dp * 16 + eq * 4;
                const float4 a = *reinterpret_cast<const float4*>(rw + idx);
                const float4 n = *reinterpret_cast<const float4*>(ns + idx);
                wq[dp][4*eq+0] = a.x + n.x;
                wq[dp][4*eq+1] = a.y + n.y;
                wq[dp][4*eq+2] = a.z + n.z;
                wq[dp][4*eq+3] = a.w + n.w;
            }
        }
    }

    // B-phase mapping
    const int qB  = lane >> 4;      // i-quarter 0..3
    const int dB  = lane & 15;
    const int swz = dB & 7;

    // coop x-tile staging: 8 b = 8192 floats; thread covers float4 idx
    // w*256 + k*64 + lane, k=0..3 (fully coalesced; LDS layout == global)
    float4 xbuf[4];
    auto xload = [&](int b0) {
        const float4* src = reinterpret_cast<const float4*>(x + b0 * 1024)
                          + (w * 256 + lane);
        #pragma unroll
        for (int k = 0; k < 4; ++k) xbuf[k] = src[k * 64];
    };
    auto xstore = [&]() {
        float4* dst = reinterpret_cast<float4*>(x_lds) + (w * 256 + lane);
        #pragma unroll
        for (int k = 0; k < 4; ++k) dst[k * 64] = xbuf[k];  // b128, 2-way free
    };

    auto aphase = [&]() {
        #pragma unroll 2
        for (int bb = 0; bb < 8; ++bb) {
            const float* xb = x_lds + bb * 1024 + lane;
            float xv[16];
            #pragma unroll
            for (int e = 0; e < 16; ++e) xv[e] = xb[e * 64]; // b32, 2-way free
            #pragma unroll
            for (int dp = 0; dp < 2; ++dp) {
                float acc = 0.f;
                #pragma unroll
                for (int e = 0; e < 16; ++e) acc = fmaf(wq[dp][e], xv[e], acc);
                const int d  = 2 * w + dp;
                const int fi = (bb * 16 + d) * 64
                             + ((((lane >> 2) ^ (d & 7)) << 2) | (lane & 3));
                p_lds[fi] = acc;    // bijective words per row: conflict-free
            }
        }
    };

    auto bread = [&](float* p) {
        const float4* pl = reinterpret_cast<const float4*>(p_lds)
                         + (w * 16 + dB) * 16;
        #pragma unroll
        for (int jj = 0; jj < 4; ++jj) {
            const float4 v = pl[(4 * qB + jj) ^ swz];  // i = qB*16+4jj..+3
            p[4*jj+0] = v.x; p[4*jj+1] = v.y;
            p[4*jj+2] = v.z; p[4*jj+3] = v.w;
        }
    };

    auto bcompute = [&](const float* p, int b0) {
        // tree-reduce sum over local 16 i
        float t0 = (p[0]+p[1]) + (p[2]+p[3]);
        float t1 = (p[4]+p[5]) + (p[6]+p[7]);
        float t2 = (p[8]+p[9]) + (p[10]+p[11]);
        float t3 = (p[12]+p[13]) + (p[14]+p[15]);
        float part = (t0 + t1) + (t2 + t3);
        part += __shfl_xor(part, 16);
        part += __shfl_xor(part, 32);
        float s = part * (1.0f / 64.0f);

        float sn = s * s;           // squash norm over d (16-lane groups)
        sn += __shfl_xor(sn, 1); sn += __shfl_xor(sn, 2);
        sn += __shfl_xor(sn, 4); sn += __shfl_xor(sn, 8);
        float factor = __builtin_amdgcn_sqrtf(sn)
                     * __builtin_amdgcn_rcpf(1.0f + sn);
        float Vsum = s * factor;

        #pragma unroll
        for (int it = 0; it < 2; ++it) {
            const float c = Vsum * 1.44269504089f;      // log2(e)
            float d0 = 0.f, d1 = 0.f, d2 = 0.f, d3 = 0.f;
            float n0 = 0.f, n1 = 0.f, n2 = 0.f, n3 = 0.f;
            #pragma unroll
            for (int k = 0; k < 4; ++k) {   // 4 independent chains, depth 4
                const float e0 = __builtin_amdgcn_exp2f(p[4*k+0] * c);
                const float e1 = __builtin_amdgcn_exp2f(p[4*k+1] * c);
                const float e2 = __builtin_amdgcn_exp2f(p[4*k+2] * c);
                const float e3 = __builtin_amdgcn_exp2f(p[4*k+3] * c);
                d0 += e0; d1 += e1; d2 += e2; d3 += e3;
                n0 = fmaf(e0, p[4*k+0], n0);
                n1 = fmaf(e1, p[4*k+1], n1);
                n2 = fmaf(e2, p[4*k+2], n2);
                n3 = fmaf(e3, p[4*k+3], n3);
            }
            float den = (d0 + d1) + (d2 + d3);
            float num = (n0 + n1) + (n2 + n3);
            den += __shfl_xor(den, 16); den += __shfl_xor(den, 32);
            num += __shfl_xor(num, 16); num += __shfl_xor(num, 32);
            s = num * __builtin_amdgcn_rcpf(den);
            sn = s * s;
            sn += __shfl_xor(sn, 1); sn += __shfl_xor(sn, 2);
            sn += __shfl_xor(sn, 4); sn += __shfl_xor(sn, 8);
            factor = __builtin_amdgcn_sqrtf(sn)
                   * __builtin_amdgcn_rcpf(1.0f + sn);
            Vsum += s * factor;
        }

        if (qB == 0)
            out[(o * 2048 + b0 + w) * 16 + dB] = s * factor;  // (1,O,B,DO)
    };

    // ---- pipeline: [xload s+1 | bcompute s] overlap (T14 split) ----
    xload(bbase);
    xstore();
    __syncthreads();                // x-tile 0 ready

    #pragma unroll
    for (int s = 0; s < NSUB; ++s) {
        const int b0 = bbase + s * 8;
        aphase();                   // x_lds -> p_lds
        __syncthreads();            // p ready; x_lds free
        float p[16];
        bread(p);
        if (s + 1 < NSUB) xload(b0 + 8);   // issue early: hides under softmax
        bcompute(p, b0);
        if (s + 1 < NSUB) xstore();        // write late
        __syncthreads();            // p-reads done & next x-tile ready
    }
}

extern "C" void kernel_launch(void* const* d_in, const int* in_sizes, int n_in,
                              void* d_out, int out_size, void* d_ws, size_t ws_size,
                              hipStream_t stream) {
    const float* x  = (const float*)d_in[0];
    const float* rw = (const float*)d_in[1];
    const float* ns = (const float*)d_in[2];
    float* out = (float*)d_out;
    (void)d_ws; (void)ws_size; (void)in_sizes; (void)n_in; (void)out_size;

    const int grid = 32 * 64;       // blockIdx = o*64 + bc
    routing_kernel<<<grid, THREADS, 0, stream>>>(x, rw, ns, out);
}

// Round 8
// 93.393 us; speedup vs baseline: 2.1227x; 1.3290x over previous
//
#include <hip/hip_runtime.h>

// Capsule routing, MI355X. B=2048, I=64, O=32, DI=DO=16, 3 iters.
// R7 post-mortem: passing p[16] by pointer into lambdas defeated SROA ->
// scratch spill (WRITE 179 MB). R8 = R7 structure, codegen-clean:
//   straight-line body, no lambdas, arrays only with constant indices,
//   all LDS addresses precomputed once (imm-offset ds ops in the loops).
// Block = 512 thr (8 waves), one o, 32 b in 4 sub-rounds of 8.
// LDS 64 KB: p_lds 32 KB + x_lds 32 KB -> 2 blocks/CU.
// A-phase: lane=i, wave w owns d-pair {2w,2w+1}; x from LDS (b32 imm reads,
//   2-way = free); swizzled conflict-free p ds_write (2 base regs + imm).
// B-phase: wave=bp, lane=(qB=lane>>4, dB=lane&15); p[16] via 4 b128 reads at
//   4 precomputed addrs (reused every sub-round); i-combine shfl_xor(16,32);
//   squash-norm over d shfl_xor(1,2,4,8); 4-chain tree reductions.
// T14 split: next x-tile global loads issued before bcompute, ds_write after.
// exp2: |arg| <= ~95 < 127 (|Vsum|<3, |p|<~26) -> no overflow w/o max-sub.
// NO min-wave forcing (R2/R5 lesson).

#define THREADS 512

__global__ __launch_bounds__(THREADS) void routing_kernel(
    const float* __restrict__ x,    // (B, DI, I) = (2048,16,64)
    const float* __restrict__ rw,   // (O, I, DO, DI) = (32,64,16,16)
    const float* __restrict__ ns,   // same
    float* __restrict__ out)        // (1, O, B, DO)
{
    __shared__ float lds[16384];    // [0,8192): priors; [8192,16384): x-tile

    const int tid  = threadIdx.x;
    const int w    = tid >> 6;      // wave 0..7
    const int lane = tid & 63;      // = i in A-phase

    const int o  = blockIdx.x >> 6;   // o-major: 64 consecutive blocks share W
    const int bc = blockIdx.x & 63;   // 32-b chunk
    const int bbase = bc * 32;

    // ---- W+noise fragment: lane=i, d in {2w, 2w+1} (32 VGPR) ----
    float wq0[16], wq1[16];
    {
        const int base = (o * 64 + lane) * 256 + w * 32;
        #pragma unroll
        for (int eq = 0; eq < 4; ++eq) {
            const float4 a0 = *reinterpret_cast<const float4*>(rw + base + eq * 4);
            const float4 n0 = *reinterpret_cast<const float4*>(ns + base + eq * 4);
            wq0[4*eq+0] = a0.x + n0.x;  wq0[4*eq+1] = a0.y + n0.y;
            wq0[4*eq+2] = a0.z + n0.z;  wq0[4*eq+3] = a0.w + n0.w;
            const float4 a1 = *reinterpret_cast<const float4*>(rw + base + 16 + eq * 4);
            const float4 n1 = *reinterpret_cast<const float4*>(ns + base + 16 + eq * 4);
            wq1[4*eq+0] = a1.x + n1.x;  wq1[4*eq+1] = a1.y + n1.y;
            wq1[4*eq+2] = a1.z + n1.z;  wq1[4*eq+3] = a1.w + n1.w;
        }
    }

    // ---- precomputed LDS addresses (reused every sub-round) ----
    const float* xrd = lds + 8192 + lane;               // A-phase x reads (imm offs)
    const int d0 = 2 * w, d1 = 2 * w + 1;
    const int perm0 = ((((lane >> 2) ^ (d0 & 7)) << 2) | (lane & 3));
    const int perm1 = ((((lane >> 2) ^ (d1 & 7)) << 2) | (lane & 3));
    float* pw0 = lds + d0 * 64 + perm0;                 // p writes (imm bb*1024)
    float* pw1 = lds + d1 * 64 + perm1;

    const int qB  = lane >> 4;      // i-quarter 0..3
    const int dB  = lane & 15;
    const int swz = dB & 7;
    const float4* prbase = reinterpret_cast<const float4*>(lds) + (w * 16 + dB) * 16;
    const float4* pr0 = prbase + ((4 * qB + 0) ^ swz);  // B-phase p reads
    const float4* pr1 = prbase + ((4 * qB + 1) ^ swz);
    const float4* pr2 = prbase + ((4 * qB + 2) ^ swz);
    const float4* pr3 = prbase + ((4 * qB + 3) ^ swz);

    float4* xwr = reinterpret_cast<float4*>(lds + 8192) + (w * 256 + lane);
    const float4* xsrc0 = reinterpret_cast<const float4*>(x) + bbase * 256
                        + (w * 256 + lane);

    const int outbase = (o * 2048 + bbase + w) * 16 + dB;

    // ---- prologue: stage x-tile 0 ----
    float4 xb0 = xsrc0[0];
    float4 xb1 = xsrc0[64];
    float4 xb2 = xsrc0[128];
    float4 xb3 = xsrc0[192];
    xwr[0] = xb0;  xwr[64] = xb1;  xwr[128] = xb2;  xwr[192] = xb3;
    __syncthreads();                // x-tile 0 ready

    #pragma unroll
    for (int s = 0; s < 4; ++s) {
        // ---- A-phase: x_lds -> p_lds (8 b's) ----
        #pragma unroll
        for (int bb = 0; bb < 8; ++bb) {
            float xv[16];
            #pragma unroll
            for (int e = 0; e < 16; ++e)
                xv[e] = xrd[bb * 1024 + e * 64];        // ds_read_b32 imm
            float acc0 = 0.f, acc1 = 0.f;
            #pragma unroll
            for (int e = 0; e < 16; ++e) {
                acc0 = fmaf(wq0[e], xv[e], acc0);
                acc1 = fmaf(wq1[e], xv[e], acc1);
            }
            pw0[bb * 1024] = acc0;                      // ds_write_b32 imm
            pw1[bb * 1024] = acc1;                      // conflict-free (bijective)
        }
        __syncthreads();            // p ready; x_lds free

        // ---- B-read: p[16] (i = qB*16 + 4jj + m) ----
        float p[16];
        {
            const float4 v0 = *pr0, v1 = *pr1, v2 = *pr2, v3 = *pr3;
            p[0]=v0.x; p[1]=v0.y; p[2]=v0.z; p[3]=v0.w;
            p[4]=v1.x; p[5]=v1.y; p[6]=v1.z; p[7]=v1.w;
            p[8]=v2.x; p[9]=v2.y; p[10]=v2.z; p[11]=v2.w;
            p[12]=v3.x; p[13]=v3.y; p[14]=v3.z; p[15]=v3.w;
        }

        // ---- T14 issue-early: next x-tile global loads ----
        if (s < 3) {
            const float4* xsrc = xsrc0 + (s + 1) * 2048;
            xb0 = xsrc[0];  xb1 = xsrc[64];  xb2 = xsrc[128];  xb3 = xsrc[192];
        }

        // ---- routing iterations ----
        // iter 0: softmax(0) uniform -> mean over i
        float t0 = (p[0]+p[1]) + (p[2]+p[3]);
        float t1 = (p[4]+p[5]) + (p[6]+p[7]);
        float t2 = (p[8]+p[9]) + (p[10]+p[11]);
        float t3 = (p[12]+p[13]) + (p[14]+p[15]);
        float part = (t0 + t1) + (t2 + t3);
        part += __shfl_xor(part, 16);
        part += __shfl_xor(part, 32);
        float sv = part * (1.0f / 64.0f);

        float sn = sv * sv;         // squash norm over d (16-lane groups)
        sn += __shfl_xor(sn, 1); sn += __shfl_xor(sn, 2);
        sn += __shfl_xor(sn, 4); sn += __shfl_xor(sn, 8);
        float factor = __builtin_amdgcn_sqrtf(sn)
                     * __builtin_amdgcn_rcpf(1.0f + sn);
        float Vsum = sv * factor;

        #pragma unroll
        for (int it = 0; it < 2; ++it) {
            const float c = Vsum * 1.44269504089f;      // log2(e)
            float e0, e1, e2, e3;
            float dd0, dd1, dd2, dd3, nn0, nn1, nn2, nn3;
            e0 = __builtin_amdgcn_exp2f(p[0] * c);
            e1 = __builtin_amdgcn_exp2f(p[1] * c);
            e2 = __builtin_amdgcn_exp2f(p[2] * c);
            e3 = __builtin_amdgcn_exp2f(p[3] * c);
            dd0 = e0; dd1 = e1; dd2 = e2; dd3 = e3;
            nn0 = e0 * p[0]; nn1 = e1 * p[1]; nn2 = e2 * p[2]; nn3 = e3 * p[3];
            e0 = __builtin_amdgcn_exp2f(p[4] * c);
            e1 = __builtin_amdgcn_exp2f(p[5] * c);
            e2 = __builtin_amdgcn_exp2f(p[6] * c);
            e3 = __builtin_amdgcn_exp2f(p[7] * c);
            dd0 += e0; dd1 += e1; dd2 += e2; dd3 += e3;
            nn0 = fmaf(e0, p[4], nn0); nn1 = fmaf(e1, p[5], nn1);
            nn2 = fmaf(e2, p[6], nn2); nn3 = fmaf(e3, p[7], nn3);
            e0 = __builtin_amdgcn_exp2f(p[8] * c);
            e1 = __builtin_amdgcn_exp2f(p[9] * c);
            e2 = __builtin_amdgcn_exp2f(p[10] * c);
            e3 = __builtin_amdgcn_exp2f(p[11] * c);
            dd0 += e0; dd1 += e1; dd2 += e2; dd3 += e3;
            nn0 = fmaf(e0, p[8], nn0);  nn1 = fmaf(e1, p[9], nn1);
            nn2 = fmaf(e2, p[10], nn2); nn3 = fmaf(e3, p[11], nn3);
            e0 = __builtin_amdgcn_exp2f(p[12] * c);
            e1 = __builtin_amdgcn_exp2f(p[13] * c);
            e2 = __builtin_amdgcn_exp2f(p[14] * c);
            e3 = __builtin_amdgcn_exp2f(p[15] * c);
            dd0 += e0; dd1 += e1; dd2 += e2; dd3 += e3;
            nn0 = fmaf(e0, p[12], nn0); nn1 = fmaf(e1, p[13], nn1);
            nn2 = fmaf(e2, p[14], nn2); nn3 = fmaf(e3, p[15], nn3);

            float den = (dd0 + dd1) + (dd2 + dd3);
            float num = (nn0 + nn1) + (nn2 + nn3);
            den += __shfl_xor(den, 16); den += __shfl_xor(den, 32);
            num += __shfl_xor(num, 16); num += __shfl_xor(num, 32);
            sv = num * __builtin_amdgcn_rcpf(den);
            sn = sv * sv;
            sn += __shfl_xor(sn, 1); sn += __shfl_xor(sn, 2);
            sn += __shfl_xor(sn, 4); sn += __shfl_xor(sn, 8);
            factor = __builtin_amdgcn_sqrtf(sn)
                   * __builtin_amdgcn_rcpf(1.0f + sn);
            Vsum += sv * factor;
        }

        if (qB == 0)
            out[outbase + s * 128] = sv * factor;       // (1,O,B,DO), b=+8 per s

        // ---- T14 write-late: store next x-tile ----
        if (s < 3) {
            xwr[0] = xb0;  xwr[64] = xb1;  xwr[128] = xb2;  xwr[192] = xb3;
        }
        __syncthreads();            // p-reads done & next x-tile ready
    }
}

extern "C" void kernel_launch(void* const* d_in, const int* in_sizes, int n_in,
                              void* d_out, int out_size, void* d_ws, size_t ws_size,
                              hipStream_t stream) {
    const float* x  = (const float*)d_in[0];
    const float* rw = (const float*)d_in[1];
    const float* ns = (const float*)d_in[2];
    float* out = (float*)d_out;
    (void)d_ws; (void)ws_size; (void)in_sizes; (void)n_in; (void)out_size;

    const int grid = 32 * 64;       // blockIdx = o*64 + bc
    routing_kernel<<<grid, THREADS, 0, stream>>>(x, rw, ns, out);
}